// Round 7
// baseline (683.510 us; speedup 1.0000x reference)
//
#include <hip/hip_runtime.h>

typedef unsigned short u16;
typedef unsigned int   u32;
typedef __attribute__((ext_vector_type(8))) short short8;
typedef __attribute__((ext_vector_type(4))) float f32x4;

constexpr int B_ = 4, S_ = 4096, DIN_ = 2048, DOUT_ = 8192;
constexpr int M_ = B_ * S_;   // 16384
constexpr int N_ = DOUT_;     // 8192
constexpr int K_ = DIN_;      // 2048
constexpr size_t NW_ = (size_t)DOUT_ * DIN_;  // 16,777,216 weights

#define GPTR(p) ((const __attribute__((address_space(1))) void*)(p))
#define LPTR(p) ((__attribute__((address_space(3))) void*)(p))

#define SB0()   __builtin_amdgcn_sched_barrier(0)
#define BAR()   asm volatile("s_barrier" ::: "memory")
#define LGKM0() asm volatile("s_waitcnt lgkmcnt(0)" ::: "memory")
#define VM0()   asm volatile("s_waitcnt vmcnt(0)" ::: "memory")

__device__ __forceinline__ u16 f2bf(float f) {
    u32 u = __float_as_uint(f);
    u += 0x7fffu + ((u >> 16) & 1u);   // round-to-nearest-even
    return (u16)(u >> 16);
}

// ---------------------------------------------------------------------------
// Pass 1: deterministic fp64 abs-sum partials.
// ---------------------------------------------------------------------------
__global__ __launch_bounds__(256)
void abssum_kernel(const float* __restrict__ w, double* __restrict__ partials)
{
    const int tid = threadIdx.x;
    const float* base = w + (size_t)blockIdx.x * 16384 + tid * 4;
    double s = 0.0;
#pragma unroll
    for (int i = 0; i < 16; ++i) {
        float4 v = *(const float4*)(base + i * 1024);
        s += (double)fabsf(v.x) + (double)fabsf(v.y)
           + (double)fabsf(v.z) + (double)fabsf(v.w);
    }
#pragma unroll
    for (int o = 32; o; o >>= 1) s += __shfl_xor(s, o, 64);
    __shared__ double red[4];
    if ((tid & 63) == 0) red[tid >> 6] = s;
    __syncthreads();
    if (tid == 0) partials[blockIdx.x] = (red[0] + red[1]) + (red[2] + red[3]);
}

__global__ __launch_bounds__(1024)
void finalize_thr(const double* __restrict__ partials, double* __restrict__ thr)
{
    __shared__ double red[1024];
    const int tid = threadIdx.x;
    red[tid] = partials[tid];
    __syncthreads();
    for (int s = 512; s > 0; s >>= 1) {
        if (tid < s) red[tid] += red[tid + s];
        __syncthreads();
    }
    if (tid == 0) *thr = red[0] * (1.0 / (double)NW_);
}

// ---------------------------------------------------------------------------
// Pass 3: ternarize W -> bf16 {-1,0,+1}; fp64 compare (threshold razor-thin).
// ---------------------------------------------------------------------------
__device__ __forceinline__ u16 tern(float w, double thr) {
    return (fabs((double)w) > thr) ? (w > 0.0f ? (u16)0x3F80u : (u16)0xBF80u)
                                   : (u16)0u;
}

__global__ __launch_bounds__(256)
void ternarize_kernel(const float* __restrict__ w, const double* __restrict__ thr_p,
                      u16* __restrict__ wt)
{
    const double thr = *thr_p;
    const size_t i = ((size_t)blockIdx.x * 256 + threadIdx.x) * 4;
    float4 v = *(const float4*)(w + i);
    union { u16 u[4]; uint2 v2; } p;
    p.u[0] = tern(v.x, thr);
    p.u[1] = tern(v.y, thr);
    p.u[2] = tern(v.z, thr);
    p.u[3] = tern(v.w, thr);
    *(uint2*)(wt + i) = p.v2;
}

// ---------------------------------------------------------------------------
// Pass 4: RMSNorm rows of x (fp32) -> bf16 xn.
// ---------------------------------------------------------------------------
__global__ __launch_bounds__(256)
void rmsnorm_kernel(const float* __restrict__ x, const float* __restrict__ gamma,
                    u16* __restrict__ xn)
{
    const int row = blockIdx.x;
    const int tid = threadIdx.x;
    const float* xr = x + (size_t)row * K_;
    float4 a = *(const float4*)(xr + tid * 8);
    float4 b = *(const float4*)(xr + tid * 8 + 4);
    float s = a.x*a.x + a.y*a.y + a.z*a.z + a.w*a.w
            + b.x*b.x + b.y*b.y + b.z*b.z + b.w*b.w;
#pragma unroll
    for (int o = 32; o; o >>= 1) s += __shfl_xor(s, o, 64);
    __shared__ float red[4];
    if ((tid & 63) == 0) red[tid >> 6] = s;
    __syncthreads();
    const float tot = (red[0] + red[1]) + (red[2] + red[3]);
    const float r = rsqrtf(tot * (1.0f / (float)K_) + 1.1920928955078125e-07f);
    float4 g0 = *(const float4*)(gamma + tid * 8);
    float4 g1 = *(const float4*)(gamma + tid * 8 + 4);
    union { u16 u[8]; uint4 v4; } p;
    p.u[0] = f2bf(a.x * r * g0.x);
    p.u[1] = f2bf(a.y * r * g0.y);
    p.u[2] = f2bf(a.z * r * g0.z);
    p.u[3] = f2bf(a.w * r * g0.w);
    p.u[4] = f2bf(b.x * r * g1.x);
    p.u[5] = f2bf(b.y * r * g1.y);
    p.u[6] = f2bf(b.z * r * g1.z);
    p.u[7] = f2bf(b.w * r * g1.w);
    *(uint4*)(xn + (size_t)row * K_ + tid * 8) = p.v4;
}

// ---------------------------------------------------------------------------
// Pass 5: GEMM  C[M,N] = xn[M,K] @ wt[N,K]^T + bias   (bf16 in, fp32 out)
// 256x256 tile, BK=64, 8 waves (2Mx4N). v7: ONE-BARRIER double-buffer K-loop.
// All prior variants (2-8 barriers/K-tile) hit 42% MfmaUtil: every segment
// ended with a full LDS drain while the matrix pipe idled. v7 makes each
// K-tile a single region: stage t+1 -> buf^1 first (HBM latency hides under
// ~3000cy of tile work), then all 24 ds_reads, then 64 MFMAs in operand-
// availability order (Q0 after 12 reads, Q2 after 20, Q1/Q3 after 24) —
// compiler's counted lgkmcnt lets the read tail drain UNDER the MFMA stream.
// Tail: LGKM0 (free — last MFMA already waited), VM0 (retires loads issued
// ~3000cy earlier; NOT the drain-own-prefetch anti-pattern), one BAR.
//
// Hazards: buf-b reads retired at LGKM0 before BAR; buf-b restage happens in
// tile t+1 after that BAR; buf^1 stage-writes retired by VM0 before t+1's
// reads. No loop-carried fragments (v3 spill lesson).
// ---------------------------------------------------------------------------
__global__ __launch_bounds__(512, 2)
void gemm_bt_kernel(const u16* __restrict__ A, const u16* __restrict__ Bt,
                    const float* __restrict__ bias, float* __restrict__ C)
{
    __shared__ u16 sm[65536];          // 128 KiB: A[2][256][64] | B[2][256][64]
    const char* smc = (const char*)sm;

    const int tid  = threadIdx.x;
    const int lane = tid & 63;
    const int wid  = tid >> 6;
    const int wm   = wid >> 2;         // 0..1
    const int wn   = wid & 3;          // 0..3
    const int hi   = lane >> 4;        // 0..3

    // XCD-aware bijective swizzle: 2048 blocks % 8 == 0
    const int swz = (blockIdx.x & 7) * 256 + (blockIdx.x >> 3);
    const int gm0 = (swz >> 5) * 256;  // 64 M-tiles
    const int gn0 = (swz & 31) * 256;  // 32 N-tiles

    // ---- staging geometry (linear LDS dest, pre-swizzled global source) ----
    const int lr8   = lane >> 3;
    const int cswel = ((lane & 7) ^ lr8) * 8;          // swizzled k-elem offset
    const int rbase = wid * 8 + lr8;                   // 0..63
    const u16* gAr = A  + (size_t)(gm0 + rbase) * K_ + cswel;
    const u16* gBr = Bt + (size_t)(gn0 + rbase) * K_ + cswel;

    auto STAGE = [&](const u16* g, int ldsu, int kt) {
        u16* d = sm + ldsu + wid * 512 + lane * 8;
        const u16* s = g + kt;
        __builtin_amdgcn_global_load_lds(GPTR(s),             LPTR(d),        16, 0, 0);
        __builtin_amdgcn_global_load_lds(GPTR(s + 64 * 2048), LPTR(d + 4096), 16, 0, 0);
    };
    // LDS u16-offsets: A buf b at b*16384 (half-tiles +0/+8192);
    //                  B buf b at 32768 + b*16384.
#define AOFF(b) ((b) * 16384)
#define BOFF(b) (32768 + (b) * 16384)

    // ---- read geometry (zero measured conflicts) ----
    const int c0 = ((hi ^ (lane & 7)) << 4);
    const int rowbyteA = (wm * 128 + (lane & 15)) * 128;
    const int rowbyteB = (wn * 64  + (lane & 15)) * 128;

#define RA(bufr, m, kk) (*(const short8*)(smc + (bufr)*32768 + rowbyteA + (m)*2048 + (c0 ^ ((kk) << 6))))
#define RB(bufr, n, kk) (*(const short8*)(smc + 65536 + (bufr)*32768 + rowbyteB + (n)*2048 + (c0 ^ ((kk) << 6))))

    f32x4 acc[8][4] = {};
    short8 a0[4][2], a1[4][2], b0[2][2], b1[2][2];

#define MFMA_BLK(AF, BF, MO, NO)                                                   \
    do {                                                                           \
        _Pragma("unroll") for (int kk = 0; kk < 2; ++kk)                           \
        _Pragma("unroll") for (int m = 0; m < 4; ++m)                              \
        _Pragma("unroll") for (int n = 0; n < 2; ++n)                              \
            acc[m + MO][n + NO] = __builtin_amdgcn_mfma_f32_16x16x32_bf16(         \
                AF[m][kk], BF[n][kk], acc[m + MO][n + NO], 0, 0, 0);               \
    } while (0)

#define READ_B0(bufr)                                                              \
    do { _Pragma("unroll") for (int n = 0; n < 2; ++n) {                           \
            b0[n][0] = RB(bufr, n, 0); b0[n][1] = RB(bufr, n, 1); } } while (0)
#define READ_B1(bufr)                                                              \
    do { _Pragma("unroll") for (int n = 0; n < 2; ++n) {                           \
            b1[n][0] = RB(bufr, n + 2, 0); b1[n][1] = RB(bufr, n + 2, 1); } } while (0)
#define READ_A0(bufr)                                                              \
    do { _Pragma("unroll") for (int m = 0; m < 4; ++m) {                           \
            a0[m][0] = RA(bufr, m, 0); a0[m][1] = RA(bufr, m, 1); } } while (0)
#define READ_A1(bufr)                                                              \
    do { _Pragma("unroll") for (int m = 0; m < 4; ++m) {                           \
            a1[m][0] = RA(bufr, m + 4, 0); a1[m][1] = RA(bufr, m + 4, 1); } } while (0)

#define PRIO_MFMA(AF, BF, MO, NO)                                                  \
    do { __builtin_amdgcn_s_setprio(1); MFMA_BLK(AF, BF, MO, NO);                  \
         __builtin_amdgcn_s_setprio(0); } while (0)

    // ---- prologue: stage buf0 @k0 ----
    STAGE(gAr,          AOFF(0),        0);
    STAGE(gAr + 262144, AOFF(0) + 8192, 0);
    STAGE(gBr,          BOFF(0),        0);
    STAGE(gBr + 262144, BOFF(0) + 8192, 0);
    VM0(); SB0(); BAR();

    for (int t = 0; t < 32; ++t) {
        const int b   = t & 1;
        const int kt1 = (t + 1) << 6;

        // stage next tile into buf^1 (issued first: latency hides under tile)
        if (t < 31) {
            STAGE(gAr,          AOFF(b ^ 1),        kt1);
            STAGE(gAr + 262144, AOFF(b ^ 1) + 8192, kt1);
            STAGE(gBr,          BOFF(b ^ 1),        kt1);
            STAGE(gBr + 262144, BOFF(b ^ 1) + 8192, kt1);
        }

        // all reads up-front; MFMAs in operand-availability order.
        READ_B0(b);
        READ_A0(b);
        READ_A1(b);
        READ_B1(b);
        PRIO_MFMA(a0, b0, 0, 0);   // Q0: ready after reads 1-12
        PRIO_MFMA(a1, b0, 4, 0);   // Q2: ready after reads 13-20
        PRIO_MFMA(a0, b1, 0, 2);   // Q1: ready after reads 21-24
        PRIO_MFMA(a1, b1, 4, 2);   // Q3

        SB0(); LGKM0(); VM0(); SB0(); BAR();
    }

    // ---- epilogue: C/D layout col=lane&15, row=hi*4+i ----
    const int orow0 = gm0 + wm * 128 + hi * 4;
    const int ocol0 = gn0 + wn * 64 + (lane & 15);
#pragma unroll
    for (int n = 0; n < 4; ++n) {
        const float bvv = bias[ocol0 + n * 16];
#pragma unroll
        for (int m = 0; m < 8; ++m) {
#pragma unroll
            for (int i = 0; i < 4; ++i) {
                C[(size_t)(orow0 + m * 16 + i) * N_ + (ocol0 + n * 16)] = acc[m][n][i] + bvv;
            }
        }
    }
#undef RA
#undef RB
#undef MFMA_BLK
#undef READ_B0
#undef READ_B1
#undef READ_A0
#undef READ_A1
#undef PRIO_MFMA
#undef AOFF
#undef BOFF
}

// ---------------------------------------------------------------------------
// Workspace layout (bytes):
//   [0,8)            : thr (double)
//   [1024, 9216)     : 1024 fp64 partials
//   [16384, +32MiB)  : wt  bf16 [N=8192][K=2048]
//   [wt_end, +64MiB) : xn  bf16 [M=16384][K=2048]
// ---------------------------------------------------------------------------
extern "C" void kernel_launch(void* const* d_in, const int* in_sizes, int n_in,
                              void* d_out, int out_size, void* d_ws, size_t ws_size,
                              hipStream_t stream)
{
    const float* x     = (const float*)d_in[0];
    const float* w     = (const float*)d_in[1];
    const float* bias  = (const float*)d_in[2];
    const float* gamma = (const float*)d_in[3];
    float* out = (float*)d_out;

    char* ws = (char*)d_ws;
    double* thr      = (double*)(ws);
    double* partials = (double*)(ws + 1024);
    u16*    wt       = (u16*)(ws + 16384);
    u16*    xn       = (u16*)(ws + 16384 + NW_ * 2);

    abssum_kernel   <<<1024,  256,  0, stream>>>(w, partials);
    finalize_thr    <<<1,     1024, 0, stream>>>(partials, thr);
    ternarize_kernel<<<16384, 256,  0, stream>>>(w, thr, wt);
    rmsnorm_kernel  <<<M_,    256,  0, stream>>>(x, gamma, xn);
    gemm_bt_kernel  <<<(M_/256)*(N_/256), 512, 0, stream>>>(xn, wt, bias, out);
}

// Round 8
// 637.218 us; speedup vs baseline: 1.0726x; 1.0726x over previous
//
#include <hip/hip_runtime.h>

typedef unsigned short u16;
typedef unsigned int   u32;
typedef __attribute__((ext_vector_type(8))) short short8;
typedef __attribute__((ext_vector_type(4))) float f32x4;

constexpr int B_ = 4, S_ = 4096, DIN_ = 2048, DOUT_ = 8192;
constexpr int M_ = B_ * S_;   // 16384
constexpr int N_ = DOUT_;     // 8192
constexpr int K_ = DIN_;      // 2048
constexpr size_t NW_ = (size_t)DOUT_ * DIN_;  // 16,777,216 weights

#define GPTR(p) ((const __attribute__((address_space(1))) void*)(p))
#define LPTR(p) ((__attribute__((address_space(3))) void*)(p))

#define SB0()   __builtin_amdgcn_sched_barrier(0)
#define BAR()   asm volatile("s_barrier" ::: "memory")
#define LGKM0() asm volatile("s_waitcnt lgkmcnt(0)" ::: "memory")
#define LGKM4() asm volatile("s_waitcnt lgkmcnt(4)" ::: "memory")
#define LGKM8() asm volatile("s_waitcnt lgkmcnt(8)" ::: "memory")
#define VM2()   asm volatile("s_waitcnt vmcnt(2)" ::: "memory")
#define VM4()   asm volatile("s_waitcnt vmcnt(4)" ::: "memory")
#define VM0()   asm volatile("s_waitcnt vmcnt(0)" ::: "memory")

__device__ __forceinline__ u16 f2bf(float f) {
    u32 u = __float_as_uint(f);
    u += 0x7fffu + ((u >> 16) & 1u);   // round-to-nearest-even
    return (u16)(u >> 16);
}

// ---------------------------------------------------------------------------
// Pass 1: deterministic fp64 abs-sum partials.
// ---------------------------------------------------------------------------
__global__ __launch_bounds__(256)
void abssum_kernel(const float* __restrict__ w, double* __restrict__ partials)
{
    const int tid = threadIdx.x;
    const float* base = w + (size_t)blockIdx.x * 16384 + tid * 4;
    double s = 0.0;
#pragma unroll
    for (int i = 0; i < 16; ++i) {
        float4 v = *(const float4*)(base + i * 1024);
        s += (double)fabsf(v.x) + (double)fabsf(v.y)
           + (double)fabsf(v.z) + (double)fabsf(v.w);
    }
#pragma unroll
    for (int o = 32; o; o >>= 1) s += __shfl_xor(s, o, 64);
    __shared__ double red[4];
    if ((tid & 63) == 0) red[tid >> 6] = s;
    __syncthreads();
    if (tid == 0) partials[blockIdx.x] = (red[0] + red[1]) + (red[2] + red[3]);
}

__global__ __launch_bounds__(1024)
void finalize_thr(const double* __restrict__ partials, double* __restrict__ thr)
{
    __shared__ double red[1024];
    const int tid = threadIdx.x;
    red[tid] = partials[tid];
    __syncthreads();
    for (int s = 512; s > 0; s >>= 1) {
        if (tid < s) red[tid] += red[tid + s];
        __syncthreads();
    }
    if (tid == 0) *thr = red[0] * (1.0 / (double)NW_);
}

// ---------------------------------------------------------------------------
// Pass 3: ternarize W -> bf16 {-1,0,+1}; fp64 compare (threshold razor-thin).
// ---------------------------------------------------------------------------
__device__ __forceinline__ u16 tern(float w, double thr) {
    return (fabs((double)w) > thr) ? (w > 0.0f ? (u16)0x3F80u : (u16)0xBF80u)
                                   : (u16)0u;
}

__global__ __launch_bounds__(256)
void ternarize_kernel(const float* __restrict__ w, const double* __restrict__ thr_p,
                      u16* __restrict__ wt)
{
    const double thr = *thr_p;
    const size_t i = ((size_t)blockIdx.x * 256 + threadIdx.x) * 4;
    float4 v = *(const float4*)(w + i);
    union { u16 u[4]; uint2 v2; } p;
    p.u[0] = tern(v.x, thr);
    p.u[1] = tern(v.y, thr);
    p.u[2] = tern(v.z, thr);
    p.u[3] = tern(v.w, thr);
    *(uint2*)(wt + i) = p.v2;
}

// ---------------------------------------------------------------------------
// Pass 4: RMSNorm rows of x (fp32) -> bf16 xn.
// ---------------------------------------------------------------------------
__global__ __launch_bounds__(256)
void rmsnorm_kernel(const float* __restrict__ x, const float* __restrict__ gamma,
                    u16* __restrict__ xn)
{
    const int row = blockIdx.x;
    const int tid = threadIdx.x;
    const float* xr = x + (size_t)row * K_;
    float4 a = *(const float4*)(xr + tid * 8);
    float4 b = *(const float4*)(xr + tid * 8 + 4);
    float s = a.x*a.x + a.y*a.y + a.z*a.z + a.w*a.w
            + b.x*b.x + b.y*b.y + b.z*b.z + b.w*b.w;
#pragma unroll
    for (int o = 32; o; o >>= 1) s += __shfl_xor(s, o, 64);
    __shared__ float red[4];
    if ((tid & 63) == 0) red[tid >> 6] = s;
    __syncthreads();
    const float tot = (red[0] + red[1]) + (red[2] + red[3]);
    const float r = rsqrtf(tot * (1.0f / (float)K_) + 1.1920928955078125e-07f);
    float4 g0 = *(const float4*)(gamma + tid * 8);
    float4 g1 = *(const float4*)(gamma + tid * 8 + 4);
    union { u16 u[8]; uint4 v4; } p;
    p.u[0] = f2bf(a.x * r * g0.x);
    p.u[1] = f2bf(a.y * r * g0.y);
    p.u[2] = f2bf(a.z * r * g0.z);
    p.u[3] = f2bf(a.w * r * g0.w);
    p.u[4] = f2bf(b.x * r * g1.x);
    p.u[5] = f2bf(b.y * r * g1.y);
    p.u[6] = f2bf(b.z * r * g1.z);
    p.u[7] = f2bf(b.w * r * g1.w);
    *(uint4*)(xn + (size_t)row * K_ + tid * 8) = p.v4;
}

// ---------------------------------------------------------------------------
// Pass 5: GEMM  C[M,N] = xn[M,K] @ wt[N,K]^T + bias   (bf16 in, fp32 out)
// 256x256 tile, BK=64, 8 waves (2Mx4N). v8: LOOKAHEAD-1 READ PIPELINE with
// PARTIAL lgkm waits (the m201 mechanism). Reads are consumed one phase after
// issue; each MFMA cluster waits only for the oldest reads (counted lgkmcnt),
// leaving the just-issued reads to drain UNDER the MFMA cluster. 4 barriers
// per K-tile; stages issue AFTER the barrier (write-after-read safety);
// counted vmcnt(2) once per tile, placed BEFORE the barrier that precedes
// the next-tile reads (cross-wave DMA visibility).
//
// Tile t (buf b=t&1), quadrants Q0(a0,b0) Q2(a1,b0) Q1(a0,b1) Q3(a1,b1):
//  p0: read a1(8); BAR; stage B-h0->b^1@kt1; lgkm(8)[retире a0,b0]; MFMA Q0
//  p1: read b1(4); BAR; stage B-h1->b^1@kt1; lgkm(4)[retire a1];    MFMA Q2
//  p2:             BAR; stage A-h0->b @kt2;  lgkm(0)[retire b1];    MFMA Q1
//      VM2 [retires buf^1 A@kt1(t-1 p2,p3) + B@kt1(t p0,p1); leaves A@kt2]
//  p3:             BAR; stage A-h1->b @kt2; read a0,b0[b^1](12);    MFMA Q3
//      (Q3 operands a1,b1 already retired at p1/p2 -> no wait)
// Hazards: B restage (p0/p1): buf^1 B reads retired by t-1 p2's lgkm(0),
// all waves past t-1 p3 BAR < t p0 BAR. A restage (p2/p3): a0 retired p0,
// a1 retired p1, stage after p2/p3 BAR. Next-tile reads (p3): preceded by
// VM2+BAR -> all waves' buf^1 stages landed. Tail: t=30 VM0, t>=30 skip A
// stages, t=31 skip B stages + reads. Loop-carried a0,b0: def (p3) strictly
// after last use (p2) -> no WAR renaming (v3 spill lesson).
// ---------------------------------------------------------------------------
__global__ __launch_bounds__(512, 2)
void gemm_bt_kernel(const u16* __restrict__ A, const u16* __restrict__ Bt,
                    const float* __restrict__ bias, float* __restrict__ C)
{
    __shared__ u16 sm[65536];          // 128 KiB: A[2][256][64] | B[2][256][64]
    const char* smc = (const char*)sm;

    const int tid  = threadIdx.x;
    const int lane = tid & 63;
    const int wid  = tid >> 6;
    const int wm   = wid >> 2;         // 0..1
    const int wn   = wid & 3;          // 0..3
    const int hi   = lane >> 4;        // 0..3

    // XCD-aware bijective swizzle: 2048 blocks % 8 == 0
    const int swz = (blockIdx.x & 7) * 256 + (blockIdx.x >> 3);
    const int gm0 = (swz >> 5) * 256;  // 64 M-tiles
    const int gn0 = (swz & 31) * 256;  // 32 N-tiles

    // ---- staging geometry (linear LDS dest, pre-swizzled global source) ----
    const int lr8   = lane >> 3;
    const int cswel = ((lane & 7) ^ lr8) * 8;          // swizzled k-elem offset
    const int rbase = wid * 8 + lr8;                   // 0..63
    const u16* gAr = A  + (size_t)(gm0 + rbase) * K_ + cswel;
    const u16* gBr = Bt + (size_t)(gn0 + rbase) * K_ + cswel;

    auto STAGE = [&](const u16* g, int ldsu, int kt) {
        u16* d = sm + ldsu + wid * 512 + lane * 8;
        const u16* s = g + kt;
        __builtin_amdgcn_global_load_lds(GPTR(s),             LPTR(d),        16, 0, 0);
        __builtin_amdgcn_global_load_lds(GPTR(s + 64 * 2048), LPTR(d + 4096), 16, 0, 0);
    };
    // LDS u16-offsets: A buf b at b*16384 (half-tiles +0/+8192);
    //                  B buf b at 32768 + b*16384.
#define AOFF(b) ((b) * 16384)
#define BOFF(b) (32768 + (b) * 16384)

    // ---- read geometry (zero measured conflicts) ----
    const int c0 = ((hi ^ (lane & 7)) << 4);
    const int rowbyteA = (wm * 128 + (lane & 15)) * 128;
    const int rowbyteB = (wn * 64  + (lane & 15)) * 128;

#define RA(bufr, m, kk) (*(const short8*)(smc + (bufr)*32768 + rowbyteA + (m)*2048 + (c0 ^ ((kk) << 6))))
#define RB(bufr, n, kk) (*(const short8*)(smc + 65536 + (bufr)*32768 + rowbyteB + (n)*2048 + (c0 ^ ((kk) << 6))))

    f32x4 acc[8][4] = {};
    short8 a0[4][2], a1[4][2], b0[2][2], b1[2][2];

#define MFMA_BLK(AF, BF, MO, NO)                                                   \
    do {                                                                           \
        _Pragma("unroll") for (int kk = 0; kk < 2; ++kk)                           \
        _Pragma("unroll") for (int m = 0; m < 4; ++m)                              \
        _Pragma("unroll") for (int n = 0; n < 2; ++n)                              \
            acc[m + MO][n + NO] = __builtin_amdgcn_mfma_f32_16x16x32_bf16(         \
                AF[m][kk], BF[n][kk], acc[m + MO][n + NO], 0, 0, 0);               \
    } while (0)

#define READ_A0B0(bufr)                                                            \
    do {                                                                           \
        _Pragma("unroll") for (int m = 0; m < 4; ++m) {                            \
            a0[m][0] = RA(bufr, m, 0); a0[m][1] = RA(bufr, m, 1); }                \
        _Pragma("unroll") for (int n = 0; n < 2; ++n) {                            \
            b0[n][0] = RB(bufr, n, 0); b0[n][1] = RB(bufr, n, 1); }                \
    } while (0)

#define READ_A1(bufr)                                                              \
    do { _Pragma("unroll") for (int m = 0; m < 4; ++m) {                           \
            a1[m][0] = RA(bufr, m + 4, 0); a1[m][1] = RA(bufr, m + 4, 1); } } while (0)
#define READ_B1(bufr)                                                              \
    do { _Pragma("unroll") for (int n = 0; n < 2; ++n) {                           \
            b1[n][0] = RB(bufr, n + 2, 0); b1[n][1] = RB(bufr, n + 2, 1); } } while (0)

#define PRIO_MFMA(AF, BF, MO, NO)                                                  \
    do { __builtin_amdgcn_s_setprio(1); MFMA_BLK(AF, BF, MO, NO);                  \
         __builtin_amdgcn_s_setprio(0); } while (0)

    // ---- prologue: buf0 A+B @k0, buf1 A @k64; retire buf0; read a0,b0 ----
    STAGE(gAr,          AOFF(0),        0);
    STAGE(gAr + 262144, AOFF(0) + 8192, 0);
    STAGE(gBr,          BOFF(0),        0);
    STAGE(gBr + 262144, BOFF(0) + 8192, 0);
    STAGE(gAr,          AOFF(1),        64);
    STAGE(gAr + 262144, AOFF(1) + 8192, 64);
    VM4(); SB0(); BAR();
    READ_A0B0(0);                       // 12 reads; retired at t=0 p0's lgkm(8)

    for (int t = 0; t < 32; ++t) {
        const int b   = t & 1;
        const int kt1 = (t + 1) << 6;
        const int kt2 = (t + 2) << 6;

        // ---- p0: read a1 | BAR | stage B-h0 | lgkm(8) | MFMA Q0 ----
        READ_A1(b);
        SB0(); BAR();
        if (t < 31) STAGE(gBr, BOFF(b ^ 1), kt1);
        LGKM8(); SB0();
        PRIO_MFMA(a0, b0, 0, 0);

        // ---- p1: read b1 | BAR | stage B-h1 | lgkm(4) | MFMA Q2 ----
        READ_B1(b);
        SB0(); BAR();
        if (t < 31) STAGE(gBr + 262144, BOFF(b ^ 1) + 8192, kt1);
        LGKM4(); SB0();
        PRIO_MFMA(a1, b0, 4, 0);

        // ---- p2: BAR | stage A-h0@kt2 | lgkm(0) | MFMA Q1 | vmcnt ----
        SB0(); BAR();
        if (t < 30) STAGE(gAr, AOFF(b), kt2);
        LGKM0(); SB0();
        PRIO_MFMA(a0, b1, 0, 2);
        SB0();
        if (t < 30) { VM2(); } else if (t == 30) { VM0(); }
        SB0();

        // ---- p3: BAR | stage A-h1@kt2 | read next a0,b0 | MFMA Q3 ----
        BAR();
        if (t < 30) STAGE(gAr + 262144, AOFF(b) + 8192, kt2);
        if (t < 31) READ_A0B0(b ^ 1);
        SB0();
        PRIO_MFMA(a1, b1, 4, 2);
    }

    // ---- epilogue: C/D layout col=lane&15, row=hi*4+i ----
    const int orow0 = gm0 + wm * 128 + hi * 4;
    const int ocol0 = gn0 + wn * 64 + (lane & 15);
#pragma unroll
    for (int n = 0; n < 4; ++n) {
        const float bvv = bias[ocol0 + n * 16];
#pragma unroll
        for (int m = 0; m < 8; ++m) {
#pragma unroll
            for (int i = 0; i < 4; ++i) {
                C[(size_t)(orow0 + m * 16 + i) * N_ + (ocol0 + n * 16)] = acc[m][n][i] + bvv;
            }
        }
    }
#undef RA
#undef RB
#undef MFMA_BLK
#undef READ_A0B0
#undef READ_A1
#undef READ_B1
#undef PRIO_MFMA
#undef AOFF
#undef BOFF
}

// ---------------------------------------------------------------------------
// Workspace layout (bytes):
//   [0,8)            : thr (double)
//   [1024, 9216)     : 1024 fp64 partials
//   [16384, +32MiB)  : wt  bf16 [N=8192][K=2048]
//   [wt_end, +64MiB) : xn  bf16 [M=16384][K=2048]
// ---------------------------------------------------------------------------
extern "C" void kernel_launch(void* const* d_in, const int* in_sizes, int n_in,
                              void* d_out, int out_size, void* d_ws, size_t ws_size,
                              hipStream_t stream)
{
    const float* x     = (const float*)d_in[0];
    const float* w     = (const float*)d_in[1];
    const float* bias  = (const float*)d_in[2];
    const float* gamma = (const float*)d_in[3];
    float* out = (float*)d_out;

    char* ws = (char*)d_ws;
    double* thr      = (double*)(ws);
    double* partials = (double*)(ws + 1024);
    u16*    wt       = (u16*)(ws + 16384);
    u16*    xn       = (u16*)(ws + 16384 + NW_ * 2);

    abssum_kernel   <<<1024,  256,  0, stream>>>(w, partials);
    finalize_thr    <<<1,     1024, 0, stream>>>(partials, thr);
    ternarize_kernel<<<16384, 256,  0, stream>>>(w, thr, wt);
    rmsnorm_kernel  <<<M_,    256,  0, stream>>>(x, gamma, xn);
    gemm_bt_kernel  <<<(M_/256)*(N_/256), 512, 0, stream>>>(xn, wt, bias, out);
}

// Round 9
// 620.125 us; speedup vs baseline: 1.1022x; 1.0276x over previous
//
#include <hip/hip_runtime.h>

typedef unsigned short u16;
typedef unsigned int   u32;
typedef __attribute__((ext_vector_type(8))) short short8;
typedef __attribute__((ext_vector_type(4))) float f32x4;

constexpr int B_ = 4, S_ = 4096, DIN_ = 2048, DOUT_ = 8192;
constexpr int M_ = B_ * S_;   // 16384
constexpr int N_ = DOUT_;     // 8192
constexpr int K_ = DIN_;      // 2048
constexpr size_t NW_ = (size_t)DOUT_ * DIN_;  // 16,777,216 weights

#define GPTR(p) ((const __attribute__((address_space(1))) void*)(p))
#define LPTR(p) ((__attribute__((address_space(3))) void*)(p))

#define SB0()   __builtin_amdgcn_sched_barrier(0)
#define BAR()   asm volatile("s_barrier" ::: "memory")
#define LGKM0() asm volatile("s_waitcnt lgkmcnt(0)" ::: "memory")
#define VM4()   asm volatile("s_waitcnt vmcnt(4)" ::: "memory")
#define VM0()   asm volatile("s_waitcnt vmcnt(0)" ::: "memory")

__device__ __forceinline__ u16 f2bf(float f) {
    u32 u = __float_as_uint(f);
    u += 0x7fffu + ((u >> 16) & 1u);   // round-to-nearest-even
    return (u16)(u >> 16);
}

// ---------------------------------------------------------------------------
// Pass 1: deterministic fp64 abs-sum partials.
// ---------------------------------------------------------------------------
__global__ __launch_bounds__(256)
void abssum_kernel(const float* __restrict__ w, double* __restrict__ partials)
{
    const int tid = threadIdx.x;
    const float* base = w + (size_t)blockIdx.x * 16384 + tid * 4;
    double s = 0.0;
#pragma unroll
    for (int i = 0; i < 16; ++i) {
        float4 v = *(const float4*)(base + i * 1024);
        s += (double)fabsf(v.x) + (double)fabsf(v.y)
           + (double)fabsf(v.z) + (double)fabsf(v.w);
    }
#pragma unroll
    for (int o = 32; o; o >>= 1) s += __shfl_xor(s, o, 64);
    __shared__ double red[4];
    if ((tid & 63) == 0) red[tid >> 6] = s;
    __syncthreads();
    if (tid == 0) partials[blockIdx.x] = (red[0] + red[1]) + (red[2] + red[3]);
}

__global__ __launch_bounds__(1024)
void finalize_thr(const double* __restrict__ partials, double* __restrict__ thr)
{
    __shared__ double red[1024];
    const int tid = threadIdx.x;
    red[tid] = partials[tid];
    __syncthreads();
    for (int s = 512; s > 0; s >>= 1) {
        if (tid < s) red[tid] += red[tid + s];
        __syncthreads();
    }
    if (tid == 0) *thr = red[0] * (1.0 / (double)NW_);
}

// ---------------------------------------------------------------------------
// Pass 3: ternarize W -> bf16 {-1,0,+1}; fp64 compare (threshold razor-thin).
// ---------------------------------------------------------------------------
__device__ __forceinline__ u16 tern(float w, double thr) {
    return (fabs((double)w) > thr) ? (w > 0.0f ? (u16)0x3F80u : (u16)0xBF80u)
                                   : (u16)0u;
}

__global__ __launch_bounds__(256)
void ternarize_kernel(const float* __restrict__ w, const double* __restrict__ thr_p,
                      u16* __restrict__ wt)
{
    const double thr = *thr_p;
    const size_t i = ((size_t)blockIdx.x * 256 + threadIdx.x) * 4;
    float4 v = *(const float4*)(w + i);
    union { u16 u[4]; uint2 v2; } p;
    p.u[0] = tern(v.x, thr);
    p.u[1] = tern(v.y, thr);
    p.u[2] = tern(v.z, thr);
    p.u[3] = tern(v.w, thr);
    *(uint2*)(wt + i) = p.v2;
}

// ---------------------------------------------------------------------------
// Pass 4: RMSNorm rows of x (fp32) -> bf16 xn.
// ---------------------------------------------------------------------------
__global__ __launch_bounds__(256)
void rmsnorm_kernel(const float* __restrict__ x, const float* __restrict__ gamma,
                    u16* __restrict__ xn)
{
    const int row = blockIdx.x;
    const int tid = threadIdx.x;
    const float* xr = x + (size_t)row * K_;
    float4 a = *(const float4*)(xr + tid * 8);
    float4 b = *(const float4*)(xr + tid * 8 + 4);
    float s = a.x*a.x + a.y*a.y + a.z*a.z + a.w*a.w
            + b.x*b.x + b.y*b.y + b.z*b.z + b.w*b.w;
#pragma unroll
    for (int o = 32; o; o >>= 1) s += __shfl_xor(s, o, 64);
    __shared__ float red[4];
    if ((tid & 63) == 0) red[tid >> 6] = s;
    __syncthreads();
    const float tot = (red[0] + red[1]) + (red[2] + red[3]);
    const float r = rsqrtf(tot * (1.0f / (float)K_) + 1.1920928955078125e-07f);
    float4 g0 = *(const float4*)(gamma + tid * 8);
    float4 g1 = *(const float4*)(gamma + tid * 8 + 4);
    union { u16 u[8]; uint4 v4; } p;
    p.u[0] = f2bf(a.x * r * g0.x);
    p.u[1] = f2bf(a.y * r * g0.y);
    p.u[2] = f2bf(a.z * r * g0.z);
    p.u[3] = f2bf(a.w * r * g0.w);
    p.u[4] = f2bf(b.x * r * g1.x);
    p.u[5] = f2bf(b.y * r * g1.y);
    p.u[6] = f2bf(b.z * r * g1.z);
    p.u[7] = f2bf(b.w * r * g1.w);
    *(uint4*)(xn + (size_t)row * K_ + tid * 8) = p.v4;
}

// ---------------------------------------------------------------------------
// Pass 5: GEMM  C[M,N] = xn[M,K] @ wt[N,K]^T + bias   (bf16 in, fp32 out)
// 256x256 tile, BK=64, 8 waves (2Mx4N). v9: 8-phase template with
// FULL-ITERATION STAGE LEAD. Iteration = 2 K-tiles: buf0@kt0=128i (p0-p3),
// buf1@kt1=128i+64 (p4-p7). Compile-time buffer indices (unrolled x2).
//
//   phase: reads         stage (->target, read at)            MFMA
//   p0   : a0,b0 (buf0)  B1h0 -> buf1@kt1      [p4-p6 this it] Q0(T0)
//   p1   : a1    (buf0)  B1h1 -> buf1@kt1      [p4-p6 this it] Q2(T0)
//   p2   : b1    (buf0)  A0h0 -> buf0@kt0+128  [p0-p1 next it] Q1(T0)
//   p3   : --            A0h1 -> buf0@kt0+128                  Q3(T0) VM4*
//   p4   : a0,b0 (buf1)  B0h0 -> buf0@kt0+128  [p0,p2 next it] Q0(T1)
//   p5   : a1    (buf1)  B0h1 -> buf0@kt0+128                  Q2(T1)
//   p6   : b1    (buf1)  A1h0 -> buf1@kt1+128  [p4-p5 next it] Q1(T1)
//   p7   : --            A1h1 -> buf1@kt1+128                  Q3(T1) VM4*
// Phase body: [reads|stage] BAR lgkm0 setprio1 16xMFMA setprio0 [VM*] BAR.
//
// vmcnt ledger (loads, 2/half-tile): each VM4 sees 12 outstanding, retires 8
// staged 4-7 phases (~2400-4200cy) earlier -> HBM latency fully hidden:
//   p3-VM4 retires {prev p4..p7, p0,p1} = B0@kt0 + A1,B1@kt1 -> p4 reads safe
//   p7-VM4 retires {p2..p5} = A0,B0@kt0+128 -> next-p0 reads safe
// WAR: A0 restage p2 (reads drained p1), B1 restage p0 (prev p6 drain),
// B0 restage p4 (p2 drain), A1 restage p6 (p5 drain) — all >=1 phase margin.
// Tail: i=15 skips kt+128 stages (p0,p1 B1@1984 still run), p3 uses VM0.
// ---------------------------------------------------------------------------
__global__ __launch_bounds__(512, 2)
void gemm_bt_kernel(const u16* __restrict__ A, const u16* __restrict__ Bt,
                    const float* __restrict__ bias, float* __restrict__ C)
{
    __shared__ u16 sm[65536];          // 128 KiB: A[2][256][64] | B[2][256][64]
    const char* smc = (const char*)sm;

    const int tid  = threadIdx.x;
    const int lane = tid & 63;
    const int wid  = tid >> 6;
    const int wm   = wid >> 2;         // 0..1
    const int wn   = wid & 3;          // 0..3
    const int hi   = lane >> 4;        // 0..3

    // XCD-aware bijective swizzle: 2048 blocks % 8 == 0
    const int swz = (blockIdx.x & 7) * 256 + (blockIdx.x >> 3);
    const int gm0 = (swz >> 5) * 256;  // 64 M-tiles
    const int gn0 = (swz & 31) * 256;  // 32 N-tiles

    // ---- staging geometry (linear LDS dest, pre-swizzled global source) ----
    const int lr8   = lane >> 3;
    const int cswel = ((lane & 7) ^ lr8) * 8;          // swizzled k-elem offset
    const int rbase = wid * 8 + lr8;                   // 0..63
    const u16* gAr  = A  + (size_t)(gm0 + rbase) * K_ + cswel;
    const u16* gBr  = Bt + (size_t)(gn0 + rbase) * K_ + cswel;
    const u16* gAr2 = gAr + 262144;                    // +128 rows
    const u16* gBr2 = gBr + 262144;

    // one half-tile (128 rows x 64 k) = 2 gload_lds/thread
    auto STAGE = [&](const u16* g, int ldsu, int kt) {
        u16* d = sm + ldsu + wid * 512 + lane * 8;
        const u16* s = g + kt;
        __builtin_amdgcn_global_load_lds(GPTR(s),             LPTR(d),        16, 0, 0);
        __builtin_amdgcn_global_load_lds(GPTR(s + 64 * 2048), LPTR(d + 4096), 16, 0, 0);
    };
    // u16 offsets: A buf0=0, A buf1=16384, B buf0=32768, B buf1=49152 (+8192=h1)

    // ---- read geometry (zero measured conflicts) ----
    const int c0 = ((hi ^ (lane & 7)) << 4);
    const int rowbyteA = (wm * 128 + (lane & 15)) * 128;
    const int rowbyteB = (wn * 64  + (lane & 15)) * 128;

#define RA(bufr, m, kk) (*(const short8*)(smc + (bufr)*32768 + rowbyteA + (m)*2048 + (c0 ^ ((kk) << 6))))
#define RB(bufr, n, kk) (*(const short8*)(smc + 65536 + (bufr)*32768 + rowbyteB + (n)*2048 + (c0 ^ ((kk) << 6))))

    f32x4 acc[8][4] = {};
    short8 a0[4][2], a1[4][2], b0[2][2], b1[2][2];

#define MFMA_BLK(AF, BF, MO, NO)                                                   \
    do {                                                                           \
        _Pragma("unroll") for (int kk = 0; kk < 2; ++kk)                           \
        _Pragma("unroll") for (int m = 0; m < 4; ++m)                              \
        _Pragma("unroll") for (int n = 0; n < 2; ++n)                              \
            acc[m + MO][n + NO] = __builtin_amdgcn_mfma_f32_16x16x32_bf16(         \
                AF[m][kk], BF[n][kk], acc[m + MO][n + NO], 0, 0, 0);               \
    } while (0)

#define READ_A0B0(bufr)                                                            \
    do {                                                                           \
        _Pragma("unroll") for (int m = 0; m < 4; ++m) {                            \
            a0[m][0] = RA(bufr, m, 0); a0[m][1] = RA(bufr, m, 1); }                \
        _Pragma("unroll") for (int n = 0; n < 2; ++n) {                            \
            b0[n][0] = RB(bufr, n, 0); b0[n][1] = RB(bufr, n, 1); }                \
    } while (0)
#define READ_A1(bufr)                                                              \
    do { _Pragma("unroll") for (int m = 0; m < 4; ++m) {                           \
            a1[m][0] = RA(bufr, m + 4, 0); a1[m][1] = RA(bufr, m + 4, 1); } } while (0)
#define READ_B1(bufr)                                                              \
    do { _Pragma("unroll") for (int n = 0; n < 2; ++n) {                           \
            b1[n][0] = RB(bufr, n + 2, 0); b1[n][1] = RB(bufr, n + 2, 1); } } while (0)

#define PRIO_MFMA(AF, BF, MO, NO)                                                  \
    do { __builtin_amdgcn_s_setprio(1); MFMA_BLK(AF, BF, MO, NO);                  \
         __builtin_amdgcn_s_setprio(0); } while (0)

    // ---- prologue: buf0 A+B @0 (4 HT), buf1 A @64 (2 HT); retire buf0 ----
    STAGE(gAr,  0,     0);
    STAGE(gAr2, 8192,  0);
    STAGE(gBr,  32768, 0);
    STAGE(gBr2, 40960, 0);
    STAGE(gAr,  16384, 64);
    STAGE(gAr2, 24576, 64);
    VM4(); SB0(); BAR();

    for (int i = 0; i < 16; ++i) {
        const int kt1  = i * 128 + 64;
        const int ktn0 = i * 128 + 128;     // buf0 next K-tile
        const int ktn1 = i * 128 + 192;     // buf1 next K-tile
        const bool f = (i < 15);

        // ---- p0: reads a0,b0(buf0) | stage B1h0@kt1 | Q0(T0) ----
        READ_A0B0(0);
        STAGE(gBr, 49152, kt1);
        SB0(); BAR(); LGKM0(); SB0();
        PRIO_MFMA(a0, b0, 0, 0);
        SB0(); BAR();

        // ---- p1: reads a1(buf0) | stage B1h1@kt1 | Q2(T0) ----
        READ_A1(0);
        STAGE(gBr2, 57344, kt1);
        SB0(); BAR(); LGKM0(); SB0();
        PRIO_MFMA(a1, b0, 4, 0);
        SB0(); BAR();

        // ---- p2: reads b1(buf0) | stage A0h0@ktn0 | Q1(T0) ----
        READ_B1(0);
        if (f) STAGE(gAr, 0, ktn0);
        SB0(); BAR(); LGKM0(); SB0();
        PRIO_MFMA(a0, b1, 0, 2);
        SB0(); BAR();

        // ---- p3: stage A0h1@ktn0 | Q3(T0) | VM4 ----
        if (f) STAGE(gAr2, 8192, ktn0);
        SB0(); BAR();
        PRIO_MFMA(a1, b1, 4, 2);
        SB0();
        if (f) { VM4(); } else { VM0(); }
        SB0(); BAR();

        // ---- p4: reads a0,b0(buf1) | stage B0h0@ktn0 | Q0(T1) ----
        READ_A0B0(1);
        if (f) STAGE(gBr, 32768, ktn0);
        SB0(); BAR(); LGKM0(); SB0();
        PRIO_MFMA(a0, b0, 0, 0);
        SB0(); BAR();

        // ---- p5: reads a1(buf1) | stage B0h1@ktn0 | Q2(T1) ----
        READ_A1(1);
        if (f) STAGE(gBr2, 40960, ktn0);
        SB0(); BAR(); LGKM0(); SB0();
        PRIO_MFMA(a1, b0, 4, 0);
        SB0(); BAR();

        // ---- p6: reads b1(buf1) | stage A1h0@ktn1 | Q1(T1) ----
        READ_B1(1);
        if (f) STAGE(gAr, 16384, ktn1);
        SB0(); BAR(); LGKM0(); SB0();
        PRIO_MFMA(a0, b1, 0, 2);
        SB0(); BAR();

        // ---- p7: stage A1h1@ktn1 | Q3(T1) | VM4 ----
        if (f) STAGE(gAr2, 24576, ktn1);
        SB0(); BAR();
        PRIO_MFMA(a1, b1, 4, 2);
        SB0();
        if (f) { VM4(); }
        SB0(); BAR();
    }

    // ---- epilogue: C/D layout col=lane&15, row=hi*4+i ----
    const int orow0 = gm0 + wm * 128 + hi * 4;
    const int ocol0 = gn0 + wn * 64 + (lane & 15);
#pragma unroll
    for (int n = 0; n < 4; ++n) {
        const float bvv = bias[ocol0 + n * 16];
#pragma unroll
        for (int m = 0; m < 8; ++m) {
#pragma unroll
            for (int i = 0; i < 4; ++i) {
                C[(size_t)(orow0 + m * 16 + i) * N_ + (ocol0 + n * 16)] = acc[m][n][i] + bvv;
            }
        }
    }
#undef RA
#undef RB
#undef MFMA_BLK
#undef READ_A0B0
#undef READ_A1
#undef READ_B1
#undef PRIO_MFMA
}

// ---------------------------------------------------------------------------
// Workspace layout (bytes):
//   [0,8)            : thr (double)
//   [1024, 9216)     : 1024 fp64 partials
//   [16384, +32MiB)  : wt  bf16 [N=8192][K=2048]
//   [wt_end, +64MiB) : xn  bf16 [M=16384][K=2048]
// ---------------------------------------------------------------------------
extern "C" void kernel_launch(void* const* d_in, const int* in_sizes, int n_in,
                              void* d_out, int out_size, void* d_ws, size_t ws_size,
                              hipStream_t stream)
{
    const float* x     = (const float*)d_in[0];
    const float* w     = (const float*)d_in[1];
    const float* bias  = (const float*)d_in[2];
    const float* gamma = (const float*)d_in[3];
    float* out = (float*)d_out;

    char* ws = (char*)d_ws;
    double* thr      = (double*)(ws);
    double* partials = (double*)(ws + 1024);
    u16*    wt       = (u16*)(ws + 16384);
    u16*    xn       = (u16*)(ws + 16384 + NW_ * 2);

    abssum_kernel   <<<1024,  256,  0, stream>>>(w, partials);
    finalize_thr    <<<1,     1024, 0, stream>>>(partials, thr);
    ternarize_kernel<<<16384, 256,  0, stream>>>(w, thr, wt);
    rmsnorm_kernel  <<<M_,    256,  0, stream>>>(x, gamma, xn);
    gemm_bt_kernel  <<<(M_/256)*(N_/256), 512, 0, stream>>>(xn, wt, bias, out);
}